// Round 1
// 489.317 us; speedup vs baseline: 1.0208x; 1.0208x over previous
//
#include <hip/hip_runtime.h>
#include <hip/hip_bf16.h>

#define NN 8192
#define DD 128
#define CC 10
#define TT 1024

typedef __attribute__((ext_vector_type(8))) short bf16x8;   // 8 bf16 in 4 VGPRs
typedef __attribute__((ext_vector_type(4))) short bf16x4;   // 4 bf16 in 2 VGPRs
typedef __attribute__((ext_vector_type(4))) float f32x4;

__device__ __forceinline__ void gload16(const void* g, void* l) {
  __builtin_amdgcn_global_load_lds(
      (const __attribute__((address_space(1))) void*)g,
      (__attribute__((address_space(3))) void*)l, 16, 0, 0);
}

__device__ __forceinline__ bf16x4 cvt4(float a, float b, float c, float d) {
  __hip_bfloat16 t[4] = {__float2bfloat16(a), __float2bfloat16(b),
                         __float2bfloat16(c), __float2bfloat16(d)};
  return *(const bf16x4*)t;
}

// ---------------- K1: class head + softmax + coefficients + s row-major ----------------
// one wave per node; s[node][256] = [s_r | s_i], coalesced writes
// reduction chains halved: u = xr.Wr - xi.Wi, v = xi.Wr + xr.Wi (linear, so reduce after combine)
__global__ __launch_bounds__(256) void k_head(
    const float* __restrict__ xr, const float* __restrict__ xi,
    const float* __restrict__ Wcr, const float* __restrict__ bcr,
    const float* __restrict__ Wci, const float* __restrict__ bci,
    const float* __restrict__ thr, const float* __restrict__ thi,
    const int* __restrict__ labels,
    __hip_bfloat16* __restrict__ s,       // [8192][256] bf16
    float* __restrict__ stats)            // [8192][4] = inr, ini, picked, lse
{
  const int lane = threadIdx.x & 63;
  const int i = blockIdx.x * 4 + (threadIdx.x >> 6);

  const float xr0 = xr[(size_t)i * DD + lane];
  const float xr1 = xr[(size_t)i * DD + 64 + lane];
  const float xi0 = xi[(size_t)i * DD + lane];
  const float xi1 = xi[(size_t)i * DD + 64 + lane];

  float pn[CC];
#pragma unroll
  for (int c = 0; c < CC; c++) {
    const float wr0 = Wcr[c * DD + lane];
    const float wr1 = Wcr[c * DD + 64 + lane];
    const float wi0 = Wci[c * DD + lane];
    const float wi1 = Wci[c * DD + 64 + lane];
    float u = xr0 * wr0 + xr1 * wr1 - xi0 * wi0 - xi1 * wi1;  // pa - pc
    float v = xi0 * wr0 + xi1 * wr1 + xr0 * wi0 + xr1 * wi1;  // pb + pd
#pragma unroll
    for (int off = 32; off > 0; off >>= 1) {
      u += __shfl_xor(u, off, 64);
      v += __shfl_xor(v, off, 64);
    }
    const float cr = u + bcr[c] - bci[c];
    const float ci = v + bcr[c] + bci[c];
    pn[c] = sqrtf(cr * cr + ci * ci);
  }
  float mx = pn[0];
#pragma unroll
  for (int c = 1; c < CC; c++) mx = fmaxf(mx, pn[c]);
  float ex[CC];
  float den = 0.f;
#pragma unroll
  for (int c = 0; c < CC; c++) { ex[c] = expf(pn[c] - mx); den += ex[c]; }
  float inr = 0.f, ini = 0.f;
#pragma unroll
  for (int c = 0; c < CC; c++) {
    const float sm = ex[c] / den;
    inr += sm * thr[c];
    ini += sm * thi[c];
  }
  // out = conj(in):  s_r = in_r*xr + in_i*xi ; s_i = in_r*xi - in_i*xr
  s[(size_t)i * 256 + lane]       = __float2bfloat16(inr * xr0 + ini * xi0);
  s[(size_t)i * 256 + 64 + lane]  = __float2bfloat16(inr * xr1 + ini * xi1);
  s[(size_t)i * 256 + 128 + lane] = __float2bfloat16(inr * xi0 - ini * xr0);
  s[(size_t)i * 256 + 192 + lane] = __float2bfloat16(inr * xi1 - ini * xr1);

  if (lane == 0) {
    const int lab = labels[i];
    float picked = pn[0];
#pragma unroll
    for (int c = 1; c < CC; c++) picked = (lab == c) ? pn[c] : picked;
    stats[i * 4 + 0] = inr;
    stats[i * 4 + 1] = ini;
    stats[i * 4 + 2] = picked;
    stats[i * 4 + 3] = mx + logf(den);
  }
}

// ---------------- K1b: tiled transpose s[8192][256] -> sT[256][8192] ----------------
__global__ __launch_bounds__(256) void k_transpose(
    const __hip_bfloat16* __restrict__ s, __hip_bfloat16* __restrict__ sT)
{
  __shared__ __hip_bfloat16 tile[64][72];   // +8 pad breaks bank alignment
  const int t = threadIdx.x;
  const int n0 = blockIdx.x * 64, f0 = blockIdx.y * 64;
  const int r = t >> 2, c = t & 3;
  const bf16x8 v0 = *(const bf16x8*)(s + (size_t)(n0 + r) * 256 + f0 + c * 16);
  const bf16x8 v1 = *(const bf16x8*)(s + (size_t)(n0 + r) * 256 + f0 + c * 16 + 8);
  *(bf16x8*)&tile[r][c * 16] = v0;
  *(bf16x8*)&tile[r][c * 16 + 8] = v1;
  __syncthreads();
  const int fr = t >> 2, nc = t & 3;
  __hip_bfloat16 o[16];
#pragma unroll
  for (int j = 0; j < 16; j++) o[j] = tile[nc * 16 + j][fr];
  *(bf16x8*)(sT + (size_t)(f0 + fr) * NN + n0 + nc * 16) = *(const bf16x8*)&o[0];
  *(bf16x8*)(sT + (size_t)(f0 + fr) * NN + n0 + nc * 16 + 8) = *(const bf16x8*)&o[8];
}

// ---------------- K2: build combined MLP weight, transposed, bf16 ----------------
__global__ __launch_bounds__(256) void k_build_bt(
    const float* __restrict__ Wr, const float* __restrict__ Wi,
    __hip_bfloat16* __restrict__ BT)
{
  const int tid = blockIdx.x * 256 + threadIdx.x;  // 65536
  const int n = tid >> 8, k = tid & 255;
  float v;
  if (n < 128) {
    v = (k < 128) ? Wr[n * 128 + k] : -Wi[n * 128 + (k - 128)];
  } else {
    v = (k < 128) ? Wi[(n - 128) * 128 + k] : Wr[(n - 128) * 128 + (k - 128)];
  }
  BT[tid] = __float2bfloat16(v);
}

// ---------------- K3: part[split] = adj_chunk @ s  (MFMA, BK=64, pipelined) ----------
// block tile 64x256, 4 waves each 64x64; grid (128 mtiles, 4 ksplit)
// T3-minimum pipeline: double-buffered LDS, next-tile loads issued before current-tile
// compute, ONE raw s_barrier per K-step with explicit vmcnt/lgkm drain (no __syncthreads,
// so next-tile global_load_lds latency hides under ds_read+MFMA of the current tile).
__global__ __launch_bounds__(256) void k_adj_gemm(
    const float* __restrict__ adj,            // [8192][8192] f32
    const __hip_bfloat16* __restrict__ sT,    // [256][8192] bf16
    float* __restrict__ part)                 // [4][8192][256] f32
{
  __shared__ __align__(16) __hip_bfloat16 As[2][64 * 32 * 2];    // 2 x 8 KB
  __shared__ __align__(16) __hip_bfloat16 Bs[2][256 * 32 * 2];   // 2 x 32 KB  (80 KB total -> 2 blk/CU)
  const int t = threadIdx.x;
  const int w = t >> 6;
  const int lane = t & 63;
  const int lm = lane & 15;
  const int kq = lane >> 4;
  const int m0 = blockIdx.x * 64;
  const int kbase = blockIdx.y * 2048;

  // A staging map: thread t covers (row=t>>2, ch2=t&3), 8 consecutive f32, both ks halves
  const float* adjp = adj + (size_t)(m0 + (t >> 2)) * NN + kbase + (t & 3) * 8;
  // B staging map: chunk p = q*256+t -> ks=p>>10, row=(p>>2)&255, kqslot=p&3 (linear LDS dest)
  const __hip_bfloat16* srcB[8];
#pragma unroll
  for (int q = 0; q < 8; q++) {
    const int p = q * 256 + t;
    srcB[q] = sT + (size_t)((p >> 2) & 255) * NN + kbase + (p >> 10) * 32 + (p & 3) * 8;
  }

  f32x4 acc[4][4];
#pragma unroll
  for (int a = 0; a < 4; a++)
#pragma unroll
    for (int b = 0; b < 4; b++) acc[a][b] = (f32x4){0.f, 0.f, 0.f, 0.f};

  // ---- prologue: stage tile 0 into buffer 0 ----
  {
    const float4 a0 = *(const float4*)(adjp);
    const float4 a1 = *(const float4*)(adjp + 4);
    const float4 a2 = *(const float4*)(adjp + 32);
    const float4 a3 = *(const float4*)(adjp + 36);
#pragma unroll
    for (int q = 0; q < 8; q++)
      gload16(srcB[q], (char*)&Bs[0][0] + (q * 256 + t) * 16);
    *(bf16x4*)&As[0][t * 8]            = cvt4(a0.x, a0.y, a0.z, a0.w);
    *(bf16x4*)&As[0][t * 8 + 4]        = cvt4(a1.x, a1.y, a1.z, a1.w);
    *(bf16x4*)&As[0][2048 + t * 8]     = cvt4(a2.x, a2.y, a2.z, a2.w);
    *(bf16x4*)&As[0][2048 + t * 8 + 4] = cvt4(a3.x, a3.y, a3.z, a3.w);
    asm volatile("s_waitcnt vmcnt(0) lgkmcnt(0)" ::: "memory");
    __builtin_amdgcn_s_barrier();
  }

#pragma unroll 2
  for (int kt = 0; kt < 32; kt++) {
    const int cur = kt & 1;
    const int nxt = cur ^ 1;
    float4 a0, a1, a2, a3;
    if (kt + 1 < 32) {
      const int knx = (kt + 1) * 64;
      // next A tile -> regs (latency hidden under this tile's compute)
      a0 = *(const float4*)(adjp + knx);
      a1 = *(const float4*)(adjp + knx + 4);
      a2 = *(const float4*)(adjp + knx + 32);
      a3 = *(const float4*)(adjp + knx + 36);
      // next B tile -> LDS (async, stays in flight across the compute below)
#pragma unroll
      for (int q = 0; q < 8; q++)
        gload16(srcB[q] + knx, (char*)&Bs[nxt][0] + (q * 256 + t) * 16);
    }
    // ---- compute current tile ----
#pragma unroll
    for (int ks = 0; ks < 2; ks++) {
      bf16x8 av[4], bv[4];
#pragma unroll
      for (int mt = 0; mt < 4; mt++)
        av[mt] = *(const bf16x8*)&As[cur][(ks * 64 + mt * 16 + lm) * 32 + kq * 8];
#pragma unroll
      for (int nt = 0; nt < 4; nt++)
        bv[nt] = *(const bf16x8*)&Bs[cur][(ks * 256 + w * 64 + nt * 16 + lm) * 32 + kq * 8];
      __builtin_amdgcn_s_setprio(1);
#pragma unroll
      for (int mt = 0; mt < 4; mt++)
#pragma unroll
        for (int nt = 0; nt < 4; nt++)
          acc[mt][nt] = __builtin_amdgcn_mfma_f32_16x16x32_bf16(av[mt], bv[nt], acc[mt][nt], 0, 0, 0);
      __builtin_amdgcn_s_setprio(0);
    }
    // ---- publish next tile ----
    if (kt + 1 < 32) {
      *(bf16x4*)&As[nxt][t * 8]            = cvt4(a0.x, a0.y, a0.z, a0.w);
      *(bf16x4*)&As[nxt][t * 8 + 4]        = cvt4(a1.x, a1.y, a1.z, a1.w);
      *(bf16x4*)&As[nxt][2048 + t * 8]     = cvt4(a2.x, a2.y, a2.z, a2.w);
      *(bf16x4*)&As[nxt][2048 + t * 8 + 4] = cvt4(a3.x, a3.y, a3.z, a3.w);
    }
    asm volatile("s_waitcnt vmcnt(0) lgkmcnt(0)" ::: "memory");
    __builtin_amdgcn_s_barrier();
  }
  // C/D layout: col = lane&15, row = (lane>>4)*4 + reg  [m89-verified]
  float* po = part + (size_t)blockIdx.y * NN * 256;
#pragma unroll
  for (int mt = 0; mt < 4; mt++)
#pragma unroll
    for (int nt = 0; nt < 4; nt++)
#pragma unroll
      for (int r = 0; r < 4; r++) {
        const int row = m0 + mt * 16 + kq * 4 + r;
        const int col = w * 64 + nt * 16 + lm;
        po[(size_t)row * 256 + col] = acc[mt][nt][r];
      }
}

// ---------------- K4a: reduce 4 split-K partials + complex scale -> msg bf16 --------
__global__ __launch_bounds__(256) void k_msg(
    const float* __restrict__ part, const float* __restrict__ stats,
    __hip_bfloat16* __restrict__ msg)   // [8192][256] = [msg_r | msg_i] bf16
{
  const int tid = blockIdx.x * 256 + threadIdx.x;  // 8192*32
  const int i = tid >> 5, c4 = tid & 31;           // 4 cols per thread
  const size_t base = (size_t)i * 256 + c4 * 4;
  float4 ar = {0.f, 0.f, 0.f, 0.f}, ai = {0.f, 0.f, 0.f, 0.f};
#pragma unroll
  for (int sp = 0; sp < 4; sp++) {
    const float4 pr = *(const float4*)(part + (size_t)sp * NN * 256 + base);
    const float4 pi = *(const float4*)(part + (size_t)sp * NN * 256 + base + 128);
    ar.x += pr.x; ar.y += pr.y; ar.z += pr.z; ar.w += pr.w;
    ai.x += pi.x; ai.y += pi.y; ai.z += pi.z; ai.w += pi.w;
  }
  const float inr = stats[i * 4 + 0], ini = stats[i * 4 + 1];
  bf16x4 mr = cvt4(inr * ar.x - ini * ai.x, inr * ar.y - ini * ai.y,
                   inr * ar.z - ini * ai.z, inr * ar.w - ini * ai.w);
  bf16x4 mi = cvt4(inr * ai.x + ini * ar.x, inr * ai.y + ini * ar.y,
                   inr * ai.z + ini * ar.z, inr * ai.w + ini * ar.w);
  *(bf16x4*)(msg + base) = mr;
  *(bf16x4*)(msg + base + 128) = mi;
}

// ---------------- K4b: MLP GEMM + bias + residual -> out (f32) ----------------
// grid (128 mtiles, 2 col halves); block tile 64x128; K=256, BK=32
// same T3-minimum pipeline: dbuf LDS, one raw barrier per K-step, loads in flight
__global__ __launch_bounds__(256) void k_mlp(
    const __hip_bfloat16* __restrict__ msg,  // [8192][256] bf16
    const __hip_bfloat16* __restrict__ BT,   // [256][256] bf16
    const float* __restrict__ br, const float* __restrict__ bi,
    const float* __restrict__ xr, const float* __restrict__ xi,
    float* __restrict__ out)                 // new_r @0, new_i @ NN*DD (f32)
{
  __shared__ __align__(16) __hip_bfloat16 As[2][64 * 32];    // 2 x 4 KB
  __shared__ __align__(16) __hip_bfloat16 Bs[2][128 * 32];   // 2 x 8 KB
  const int t = threadIdx.x;
  const int w = t >> 6;
  const int lane = t & 63;
  const int lm = lane & 15, kq = lane >> 4;
  const int m0 = blockIdx.x * 64;
  const int by = blockIdx.y;

  const __hip_bfloat16* srcA = msg + (size_t)(m0 + (t >> 2)) * 256 + (t & 3) * 8;
  const __hip_bfloat16* srcB0 = BT + (size_t)(by * 128 + (t >> 2)) * 256 + (t & 3) * 8;
  const __hip_bfloat16* srcB1 = BT + (size_t)(by * 128 + 64 + (t >> 2)) * 256 + (t & 3) * 8;

  f32x4 acc[4][2];
#pragma unroll
  for (int a = 0; a < 4; a++)
#pragma unroll
    for (int b = 0; b < 2; b++) acc[a][b] = (f32x4){0.f, 0.f, 0.f, 0.f};

  // prologue: stage tile 0
  gload16(srcA, (char*)&As[0][0] + t * 16);
  gload16(srcB0, (char*)&Bs[0][0] + t * 16);
  gload16(srcB1, (char*)&Bs[0][0] + (256 + t) * 16);
  asm volatile("s_waitcnt vmcnt(0)" ::: "memory");
  __builtin_amdgcn_s_barrier();

#pragma unroll
  for (int kt = 0; kt < 8; kt++) {
    const int cur = kt & 1, nxt = cur ^ 1;
    if (kt + 1 < 8) {
      const int koff = (kt + 1) * 32;
      gload16(srcA + koff, (char*)&As[nxt][0] + t * 16);
      gload16(srcB0 + koff, (char*)&Bs[nxt][0] + t * 16);
      gload16(srcB1 + koff, (char*)&Bs[nxt][0] + (256 + t) * 16);
    }
    bf16x8 av[4], bv[2];
#pragma unroll
    for (int mt = 0; mt < 4; mt++)
      av[mt] = *(const bf16x8*)&As[cur][(mt * 16 + lm) * 32 + kq * 8];
#pragma unroll
    for (int nt = 0; nt < 2; nt++)
      bv[nt] = *(const bf16x8*)&Bs[cur][(w * 32 + nt * 16 + lm) * 32 + kq * 8];
    __builtin_amdgcn_s_setprio(1);
#pragma unroll
    for (int mt = 0; mt < 4; mt++)
#pragma unroll
      for (int nt = 0; nt < 2; nt++)
        acc[mt][nt] = __builtin_amdgcn_mfma_f32_16x16x32_bf16(av[mt], bv[nt], acc[mt][nt], 0, 0, 0);
    __builtin_amdgcn_s_setprio(0);
    asm volatile("s_waitcnt vmcnt(0)" ::: "memory");
    __builtin_amdgcn_s_barrier();
  }
  const float* resid = by ? xi : xr;
  const float sg = by ? 1.f : -1.f;   // yr: b_r - b_i ; yi: b_r + b_i
#pragma unroll
  for (int mt = 0; mt < 4; mt++)
#pragma unroll
    for (int nt = 0; nt < 2; nt++)
#pragma unroll
      for (int r = 0; r < 4; r++) {
        const int i = m0 + mt * 16 + kq * 4 + r;
        const int j = w * 32 + nt * 16 + lm;
        out[(size_t)by * (NN * DD) + (size_t)i * DD + j] =
            acc[mt][nt][r] + br[j] + sg * bi[j] + resid[(size_t)i * DD + j];
      }
}

// ---------------- K5: losses (f32 out) ----------------
__global__ __launch_bounds__(1024) void k_loss(
    const float* __restrict__ thi, const int* __restrict__ tix,
    const float* __restrict__ stats, float* __restrict__ out2)
{
  __shared__ float red[16];
  const int t = threadIdx.x;
  const int idx = tix[t];
  float v = stats[idx * 4 + 2] - stats[idx * 4 + 3];  // logp at label = picked - lse
#pragma unroll
  for (int off = 32; off > 0; off >>= 1) v += __shfl_xor(v, off, 64);
  if ((t & 63) == 0) red[t >> 6] = v;
  __syncthreads();
  if (t == 0) {
    float s = 0.f;
    for (int q = 0; q < 16; q++) s += red[q];
    const float sup = -0.1f * (s / (float)TT);
    float th[CC];
    for (int c = 0; c < CC; c++) th[c] = thi[c];
    for (int a = 1; a < CC; a++) {        // insertion sort ascending
      const float key = th[a];
      int b = a - 1;
      while (b >= 0 && th[b] > key) { th[b + 1] = th[b]; b--; }
      th[b + 1] = key;
    }
    float dsum = 0.f, dmax = 0.f;
    for (int a = 0; a < CC - 1; a++) {
      const float d = fabsf(th[a] - th[a + 1]);
      dsum += d;
      dmax = fmaxf(dmax, d);
    }
    const float difference = dsum / (dmax + 1e-6f);
    out2[0] = 0.1f / (1e-6f + difference);  // separate_loss
    out2[1] = sup;                          // supervised_loss
  }
}

extern "C" void kernel_launch(void* const* d_in, const int* in_sizes, int n_in,
                              void* d_out, int out_size, void* d_ws, size_t ws_size,
                              hipStream_t stream) {
  const float* xr  = (const float*)d_in[0];
  const float* xi  = (const float*)d_in[1];
  const float* adj = (const float*)d_in[2];
  const float* thr = (const float*)d_in[3];
  const float* thi = (const float*)d_in[4];
  const float* Wr  = (const float*)d_in[5];
  const float* br  = (const float*)d_in[6];
  const float* Wi  = (const float*)d_in[7];
  const float* bi  = (const float*)d_in[8];
  const float* Wcr = (const float*)d_in[9];
  const float* bcr = (const float*)d_in[10];
  const float* Wci = (const float*)d_in[11];
  const float* bci = (const float*)d_in[12];
  const int* labels = (const int*)d_in[13];
  const int* tix    = (const int*)d_in[14];
  float* out = (float*)d_out;

  // workspace layout (~40.4 MB):
  //   [0,4MB)     s [8192][256] bf16 (row-major); reused as msg after k_transpose
  //   [4,8MB)     sT [256][8192] bf16
  //   [8,40MB)    part [4][8192][256] f32
  //   [40MB,+128K)  stats [8192][4] f32
  //   [40MB+128K,+128K) BT [256][256] bf16
  char* ws = (char*)d_ws;
  __hip_bfloat16* s    = (__hip_bfloat16*)(ws);
  __hip_bfloat16* sT   = (__hip_bfloat16*)(ws + (size_t)4 * 1024 * 1024);
  float*          part = (float*)(ws + (size_t)8 * 1024 * 1024);
  float*          stats= (float*)(ws + (size_t)40 * 1024 * 1024);
  __hip_bfloat16* BT   = (__hip_bfloat16*)(ws + (size_t)40 * 1024 * 1024 + 131072);
  __hip_bfloat16* msg  = s;   // s dead after k_transpose

  k_head<<<NN / 4, 256, 0, stream>>>(xr, xi, Wcr, bcr, Wci, bci, thr, thi, labels, s, stats);
  k_transpose<<<dim3(NN / 64, 4), 256, 0, stream>>>(s, sT);
  k_build_bt<<<256, 256, 0, stream>>>(Wr, Wi, BT);
  k_adj_gemm<<<dim3(128, 4), 256, 0, stream>>>(adj, sT, part);
  k_msg<<<NN * 32 / 256, 256, 0, stream>>>(part, stats, msg);
  k_mlp<<<dim3(128, 2), 256, 0, stream>>>(msg, BT, br, bi, xr, xi, out);
  k_loss<<<1, TT, 0, stream>>>(thi, tix, stats, out + (size_t)2 * NN * DD);
}